// Round 1
// baseline (1069.008 us; speedup 1.0000x reference)
//
#include <hip/hip_runtime.h>
#include <stdint.h>

#define NNODES 50000
#define NEDGES 1600000
#define HD 256
#define EPSV 1e-5f

typedef unsigned short u16;
typedef __attribute__((ext_vector_type(8))) short short8;
typedef __attribute__((ext_vector_type(4))) float f32x4;

__device__ __forceinline__ u16 f2b(float f) {
  union { float f; uint32_t u; } c; c.f = f;
  uint32_t u = c.u;
  u += 0x7fffu + ((u >> 16) & 1u);   // round-to-nearest-even
  return (u16)(u >> 16);
}
__device__ __forceinline__ float b2f(u16 s) {
  union { uint32_t u; float f; } c; c.u = ((uint32_t)s) << 16;
  return c.f;
}

// ---------------- small setup kernels ----------------

__global__ void init_k(int* __restrict__ deg, int* __restrict__ cur, float* __restrict__ st) {
  int i = blockIdx.x * 256 + threadIdx.x;
  if (i < NNODES) { deg[i] = 1; cur[i] = 0; }   // deg starts at 1: self-loop
  if (i < 4 * 512) st[i] = 0.f;
}

// w1 [168,256] fp32 -> W1T [256][192] bf16 (k-contiguous, zero-padded K)
__global__ void cw1_k(const float* __restrict__ w1, u16* __restrict__ W1T) {
  int n = blockIdx.x, k = threadIdx.x;  // block 192 threads
  W1T[n * 192 + k] = (k < 168) ? f2b(w1[k * HD + n]) : (u16)0;
}

// Mc [256][192] = [tbW@basis_b || tfW@basis_f]
__global__ void mc_k(const float* __restrict__ tbW, const float* __restrict__ tfW,
                     const float* __restrict__ bb, const float* __restrict__ bf,
                     float* __restrict__ Mc) {
  int k = blockIdx.x, n = threadIdx.x;  // block 192 threads
  float s = 0.f;
  if (n < 168) {
    for (int i = 0; i < 167; ++i) s += tbW[k * 167 + i] * bb[i * 168 + n];
  } else {
    int n2 = n - 168;
    for (int i = 0; i < 23; ++i) s += tfW[k * 23 + i] * bf[i * 24 + n2];
  }
  Mc[k * 192 + n] = s;
}

__global__ void count_k(const int* __restrict__ dst, int* __restrict__ deg) {
  int e = blockIdx.x * 256 + threadIdx.x;
  if (e < NEDGES) atomicAdd(&deg[dst[e]], 1);
}

__global__ __launch_bounds__(1024) void scan_k(const int* __restrict__ deg,
                                               int* __restrict__ offa, float* __restrict__ dinv) {
  const int T = 1024;
  int t = threadIdx.x;
  int chunk = (NNODES + T - 1) / T;
  int a = t * chunk, b = min(a + chunk, NNODES);
  int s = 0;
  for (int i = a; i < b; ++i) s += deg[i];
  __shared__ int red[T];
  red[t] = s;
  __syncthreads();
  for (int d = 1; d < T; d <<= 1) {
    int v = (t >= d) ? red[t - d] : 0;
    __syncthreads();
    red[t] += v;
    __syncthreads();
  }
  int run = (t > 0) ? red[t - 1] : 0;
  for (int i = a; i < b; ++i) {
    offa[i] = run;
    run += deg[i];
    dinv[i] = rsqrtf((float)deg[i]);
  }
  if (t == T - 1) offa[NNODES] = run;
}

__global__ void fill_k(const int* __restrict__ src, const int* __restrict__ dst,
                       const int* __restrict__ offa, int* __restrict__ cur, int* __restrict__ csr) {
  int t = blockIdx.x * 256 + threadIdx.x;
  if (t < NEDGES) {
    int d = dst[t];
    int p = atomicAdd(&cur[d], 1);
    csr[offa[d] + p] = src[t];
  } else if (t < NEDGES + NNODES) {
    int i = t - NEDGES;
    int p = atomicAdd(&cur[i], 1);
    csr[offa[i] + p] = i;   // self loop
  }
}

// ---------------- MFMA GEMM: [M x K] @ WT^T -> [M x NT*16] ----------------
// WT is [NT*16][Kpad] bf16, k-contiguous (pre-transposed, BN-folded).
// Epilogue: + extra[col]; optional ReLU; store bf16 to ws, or (SPLIT) fp32 split to backcast/forecast.
template <int NT, bool AF32, bool RELU, bool SPLIT>
__global__ __launch_bounds__(256) void gemm_k(const void* __restrict__ Ap, int M, int Kpad,
                                              int lda, int Klim,
                                              const u16* __restrict__ WT,
                                              const float* __restrict__ extra,
                                              void* __restrict__ outp, float* __restrict__ out2) {
  __shared__ __align__(16) u16 Alds[64][32];
  __shared__ __align__(16) u16 Blds[NT * 16][32];
  const int tid = threadIdx.x;
  const int wave = tid >> 6, lane = tid & 63;
  const int quad = lane >> 4, l16 = lane & 15;
  const int row0 = blockIdx.x * 64;

  f32x4 acc[NT];
#pragma unroll
  for (int i = 0; i < NT; ++i) acc[i] = (f32x4){0.f, 0.f, 0.f, 0.f};

  const int am = tid >> 2;            // 0..63 tile row
  const int akc = (tid & 3) * 8;      // 0,8,16,24 k-chunk
  const int arow = row0 + am;

  for (int k0 = 0; k0 < Kpad; k0 += 32) {
    // --- stage A tile [64][32] ---
    uint4 pack = {0u, 0u, 0u, 0u};
    if constexpr (AF32) {
      const float* A = (const float*)Ap;
      if (arow < M && (k0 + akc) < Klim) {
        const float* p = A + (size_t)arow * lda + k0 + akc;
        float4 fa = *(const float4*)p;
        float4 fb = *(const float4*)(p + 4);
        pack.x = (uint32_t)f2b(fa.x) | ((uint32_t)f2b(fa.y) << 16);
        pack.y = (uint32_t)f2b(fa.z) | ((uint32_t)f2b(fa.w) << 16);
        pack.z = (uint32_t)f2b(fb.x) | ((uint32_t)f2b(fb.y) << 16);
        pack.w = (uint32_t)f2b(fb.z) | ((uint32_t)f2b(fb.w) << 16);
      }
    } else {
      const u16* A = (const u16*)Ap;
      if (arow < M) pack = *(const uint4*)&A[(size_t)arow * lda + k0 + akc];
    }
    *(uint4*)&Alds[am][akc] = pack;
    // --- stage B tile [NT*16][32] (already k-contiguous) ---
    if (tid < NT * 16) {
      const u16* srcp = &WT[(size_t)tid * Kpad + k0];
      uint4 b0 = *(const uint4*)(srcp);
      uint4 b1 = *(const uint4*)(srcp + 8);
      uint4 b2 = *(const uint4*)(srcp + 16);
      uint4 b3 = *(const uint4*)(srcp + 24);
      *(uint4*)&Blds[tid][0] = b0;
      *(uint4*)&Blds[tid][8] = b1;
      *(uint4*)&Blds[tid][16] = b2;
      *(uint4*)&Blds[tid][24] = b3;
    }
    __syncthreads();
    short8 av = *(const short8*)&Alds[wave * 16 + l16][quad * 8];
#pragma unroll
    for (int nt = 0; nt < NT; ++nt) {
      short8 bv = *(const short8*)&Blds[nt * 16 + l16][quad * 8];
      acc[nt] = __builtin_amdgcn_mfma_f32_16x16x32_bf16(av, bv, acc[nt], 0, 0, 0);
    }
    __syncthreads();
  }

  // --- epilogue: C/D layout col = lane&15, row = quad*4 + reg ---
#pragma unroll
  for (int nt = 0; nt < NT; ++nt) {
#pragma unroll
    for (int r = 0; r < 4; ++r) {
      int row = row0 + wave * 16 + quad * 4 + r;
      if (row >= M) continue;
      int col = nt * 16 + l16;
      float v = acc[nt][r] + extra[col];
      if constexpr (RELU) v = fmaxf(v, 0.f);
      if constexpr (SPLIT) {
        if (col < 168) ((float*)outp)[(size_t)row * 168 + col] = v;
        else ((float*)out2)[(size_t)row * 24 + (col - 168)] = v;
      } else {
        ((u16*)outp)[(size_t)row * (NT * 16) + col] = f2b(v);
      }
    }
  }
}

// ---------------- BN stats: per-feature sum / sumsq ----------------
__global__ __launch_bounds__(256) void stats_k(const u16* __restrict__ a, int M,
                                               float* __restrict__ st) {
  int t = threadIdx.x;
  int r0 = blockIdx.x * 64;
  int r1 = min(r0 + 64, M);
  float s = 0.f, q = 0.f;
  for (int r = r0; r < r1; ++r) {
    float v = b2f(a[(size_t)r * HD + t]);
    s += v;
    q += v * v;
  }
  atomicAdd(&st[t], s);
  atomicAdd(&st[HD + t], q);
}

// ---------------- fold BN(stats,gamma,beta) into next weight ----------------
// W [256][ncols] fp32 -> WT [ncols][256] bf16 (k-contiguous); extra[n] = bias[n] + sum_k shift_k*W[k][n]
__global__ __launch_bounds__(256) void fold_k(const float* __restrict__ st, float invM,
                                              const float* __restrict__ gamma,
                                              const float* __restrict__ beta,
                                              const float* __restrict__ W, int ncols,
                                              const float* __restrict__ bias,
                                              u16* __restrict__ WT, float* __restrict__ extra) {
  int n = blockIdx.x, k = threadIdx.x;
  float m = st[k] * invM;
  float v = st[HD + k] * invM - m * m;
  float sc = gamma[k] * rsqrtf(v + EPSV);
  float sh = beta[k] - m * sc;
  float w = W[(size_t)k * ncols + n];
  WT[(size_t)n * HD + k] = f2b(sc * w);
  __shared__ float red[256];
  red[k] = sh * w;
  __syncthreads();
  for (int d = 128; d > 0; d >>= 1) {
    if (k < d) red[k] += red[k + d];
    __syncthreads();
  }
  if (k == 0) extra[n] = (bias ? bias[n] : 0.f) + red[0];
}

// ---------------- GCN aggregation: one wave per dst node ----------------
__global__ __launch_bounds__(256) void agg_k(const int* __restrict__ csr, const int* __restrict__ offa,
                                             const float* __restrict__ dinv, const u16* __restrict__ xw,
                                             const float* __restrict__ gb, u16* __restrict__ out) {
  int wave = threadIdx.x >> 6, lane = threadIdx.x & 63;
  int dst = blockIdx.x * 4 + wave;
  if (dst >= NNODES) return;
  int p0 = offa[dst], p1 = offa[dst + 1];
  float a0 = 0.f, a1 = 0.f, a2 = 0.f, a3 = 0.f;
  const int c = lane * 4;
  for (int p = p0; p < p1; ++p) {
    int s = csr[p];
    float wgt = dinv[s];
    uint2 v = *(const uint2*)&xw[(size_t)s * HD + c];
    a0 += wgt * b2f((u16)(v.x & 0xffffu));
    a1 += wgt * b2f((u16)(v.x >> 16));
    a2 += wgt * b2f((u16)(v.y & 0xffffu));
    a3 += wgt * b2f((u16)(v.y >> 16));
  }
  float dd = dinv[dst];
  float4 gv = *(const float4*)&gb[c];
  float r0 = fmaxf(dd * a0 + gv.x, 0.f);
  float r1 = fmaxf(dd * a1 + gv.y, 0.f);
  float r2 = fmaxf(dd * a2 + gv.z, 0.f);
  float r3 = fmaxf(dd * a3 + gv.w, 0.f);
  uint2 o;
  o.x = (uint32_t)f2b(r0) | ((uint32_t)f2b(r1) << 16);
  o.y = (uint32_t)f2b(r2) | ((uint32_t)f2b(r3) << 16);
  *(uint2*)&out[(size_t)dst * HD + c] = o;
}

// ---------------- launch ----------------

extern "C" void kernel_launch(void* const* d_in, const int* in_sizes, int n_in,
                              void* d_out, int out_size, void* d_ws, size_t ws_size,
                              hipStream_t stream) {
  const float* x = (const float*)d_in[0];
  const int* ei = (const int*)d_in[1];
  const float* w1 = (const float*)d_in[2];
  const float* b1 = (const float*)d_in[3];
  const float* g1 = (const float*)d_in[4];
  const float* bt1 = (const float*)d_in[5];
  const float* w2 = (const float*)d_in[6];
  const float* b2 = (const float*)d_in[7];
  const float* g2 = (const float*)d_in[8];
  const float* bt2 = (const float*)d_in[9];
  const float* gw1 = (const float*)d_in[10];
  const float* gb1 = (const float*)d_in[11];
  const float* gg1 = (const float*)d_in[12];
  const float* gbt1 = (const float*)d_in[13];
  const float* gw2 = (const float*)d_in[14];
  const float* gb2 = (const float*)d_in[15];
  const float* gg2 = (const float*)d_in[16];
  const float* gbt2 = (const float*)d_in[17];
  const float* tbW = (const float*)d_in[18];
  const float* tfW = (const float*)d_in[19];
  const float* bb = (const float*)d_in[20];
  const float* bfb = (const float*)d_in[21];
  const int* esrc = ei;
  const int* edst = ei + NEDGES;

  char* wsp = (char*)d_ws;
  size_t off = 0;
  auto alloc = [&](size_t b) {
    void* p = wsp + off;
    off += (b + 511) & ~(size_t)511;
    return p;
  };
  u16* buf1 = (u16*)alloc((size_t)NNODES * HD * 2);
  u16* buf2 = (u16*)alloc((size_t)NNODES * HD * 2);
  int* csr = (int*)alloc((size_t)(NEDGES + NNODES) * 4);
  int* deg = (int*)alloc((size_t)NNODES * 4);
  int* cur = (int*)alloc((size_t)NNODES * 4);
  int* offa = (int*)alloc((size_t)(NNODES + 1) * 4);
  float* dinv = (float*)alloc((size_t)NNODES * 4);
  float* st = (float*)alloc(4 * 512 * 4);
  u16* W1T = (u16*)alloc(256 * 192 * 2);
  u16* WT = (u16*)alloc(256 * 256 * 2);
  float* Mc = (float*)alloc(256 * 192 * 4);
  float* extra = (float*)alloc(256 * 4);

  float* backc = (float*)d_out;
  float* forec = backc + (size_t)NNODES * 168;
  const float invM = 1.0f / (float)NNODES;

  const int GB = (NNODES + 63) / 64;  // 782

  init_k<<<196, 256, 0, stream>>>(deg, cur, st);
  cw1_k<<<256, 192, 0, stream>>>(w1, W1T);
  mc_k<<<256, 192, 0, stream>>>(tbW, tfW, bb, bfb, Mc);
  count_k<<<NEDGES / 256, 256, 0, stream>>>(edst, deg);
  scan_k<<<1, 1024, 0, stream>>>(deg, offa, dinv);
  fill_k<<<(NEDGES + NNODES + 255) / 256, 256, 0, stream>>>(esrc, edst, offa, cur, csr);

  // MLP layer 1: a1 = ReLU(x@w1 + b1)
  gemm_k<16, true, true, false><<<GB, 256, 0, stream>>>(x, NNODES, 192, 168, 168, W1T, b1, buf1, nullptr);
  stats_k<<<GB, 256, 0, stream>>>(buf1, NNODES, st);
  // fold BN1 into w2 (+b2)
  fold_k<<<256, 256, 0, stream>>>(st, invM, g1, bt1, w2, 256, b2, WT, extra);
  // MLP layer 2: a2 = ReLU(BN1(a1)@w2 + b2)
  gemm_k<16, false, true, false><<<GB, 256, 0, stream>>>(buf1, NNODES, 256, 256, 256, WT, extra, buf2, nullptr);
  stats_k<<<GB, 256, 0, stream>>>(buf2, NNODES, st + 512);
  // fold BN2 into gw1 (no bias: gb1 added after aggregation)
  fold_k<<<256, 256, 0, stream>>>(st + 512, invM, g2, bt2, gw1, 256, nullptr, WT, extra);
  // xw1 = BN2(a2)@gw1
  gemm_k<16, false, false, false><<<GB, 256, 0, stream>>>(buf2, NNODES, 256, 256, 256, WT, extra, buf1, nullptr);
  // g1a = ReLU(aggregate(xw1) + gb1)
  agg_k<<<12500, 256, 0, stream>>>(csr, offa, dinv, buf1, gb1, buf2);
  stats_k<<<GB, 256, 0, stream>>>(buf2, NNODES, st + 1024);
  // fold BN3 into gw2
  fold_k<<<256, 256, 0, stream>>>(st + 1024, invM, gg1, gbt1, gw2, 256, nullptr, WT, extra);
  // xw2 = BN3(g1a)@gw2
  gemm_k<16, false, false, false><<<GB, 256, 0, stream>>>(buf2, NNODES, 256, 256, 256, WT, extra, buf1, nullptr);
  // g2a = ReLU(aggregate(xw2) + gb2)
  agg_k<<<12500, 256, 0, stream>>>(csr, offa, dinv, buf1, gb2, buf2);
  stats_k<<<GB, 256, 0, stream>>>(buf2, NNODES, st + 1536);
  // fold BN4 into Mc [256][192]
  fold_k<<<192, 256, 0, stream>>>(st + 1536, invM, gg2, gbt2, Mc, 192, nullptr, WT, extra);
  // final: [backcast || forecast] = BN4(g2a) @ Mc
  gemm_k<12, false, false, true><<<GB, 256, 0, stream>>>(buf2, NNODES, 256, 256, 256, WT, extra, backc, forec);
}

// Round 2
// 929.858 us; speedup vs baseline: 1.1496x; 1.1496x over previous
//
#include <hip/hip_runtime.h>
#include <stdint.h>

#define NNODES 50000
#define NEDGES 1600000
#define HD 256
#define EPSV 1e-5f

typedef unsigned short u16;
typedef __attribute__((ext_vector_type(8))) short short8;
typedef __attribute__((ext_vector_type(4))) float f32x4;

__device__ __forceinline__ u16 f2b(float f) {
  union { float f; uint32_t u; } c; c.f = f;
  uint32_t u = c.u;
  u += 0x7fffu + ((u >> 16) & 1u);   // round-to-nearest-even
  return (u16)(u >> 16);
}
__device__ __forceinline__ float b2f(u16 s) {
  union { uint32_t u; float f; } c; c.u = ((uint32_t)s) << 16;
  return c.f;
}

// async 16B global -> LDS (direct-to-shared DMA). LDS dst must be
// wave-uniform base + lane*16 — our tid*16 flat mappings satisfy this.
__device__ __forceinline__ void gl2lds16(const u16* g, u16* l) {
  __builtin_amdgcn_global_load_lds(
      (__attribute__((address_space(1))) void*)(void*)g,
      (__attribute__((address_space(3))) void*)(void*)l, 16, 0, 0);
}

// ---------------- small setup kernels ----------------

__global__ void init_k(int* __restrict__ deg, int* __restrict__ cur, float* __restrict__ st) {
  int i = blockIdx.x * 256 + threadIdx.x;
  if (i < NNODES) { deg[i] = 1; cur[i] = 0; }   // deg starts at 1: self-loop
  if (i < 4 * 512) st[i] = 0.f;
}

// w1 [168,256] fp32 -> W1T [256][192] bf16 (k-contiguous, zero-padded K)
__global__ void cw1_k(const float* __restrict__ w1, u16* __restrict__ W1T) {
  int n = blockIdx.x, k = threadIdx.x;  // block 192 threads
  W1T[n * 192 + k] = (k < 168) ? f2b(w1[k * HD + n]) : (u16)0;
}

// Mc [256][192] = [tbW@basis_b || tfW@basis_f]
__global__ void mc_k(const float* __restrict__ tbW, const float* __restrict__ tfW,
                     const float* __restrict__ bb, const float* __restrict__ bf,
                     float* __restrict__ Mc) {
  int k = blockIdx.x, n = threadIdx.x;  // block 192 threads
  float s = 0.f;
  if (n < 168) {
    for (int i = 0; i < 167; ++i) s += tbW[k * 167 + i] * bb[i * 168 + n];
  } else {
    int n2 = n - 168;
    for (int i = 0; i < 23; ++i) s += tfW[k * 23 + i] * bf[i * 24 + n2];
  }
  Mc[k * 192 + n] = s;
}

__global__ void count_k(const int* __restrict__ dst, int* __restrict__ deg) {
  int e = blockIdx.x * 256 + threadIdx.x;
  if (e < NEDGES) atomicAdd(&deg[dst[e]], 1);
}

__global__ __launch_bounds__(1024) void scan_k(const int* __restrict__ deg,
                                               int* __restrict__ offa, float* __restrict__ dinv) {
  const int T = 1024;
  int t = threadIdx.x;
  int chunk = (NNODES + T - 1) / T;
  int a = t * chunk, b = min(a + chunk, NNODES);
  int s = 0;
  for (int i = a; i < b; ++i) s += deg[i];
  __shared__ int red[T];
  red[t] = s;
  __syncthreads();
  for (int d = 1; d < T; d <<= 1) {
    int v = (t >= d) ? red[t - d] : 0;
    __syncthreads();
    red[t] += v;
    __syncthreads();
  }
  int run = (t > 0) ? red[t - 1] : 0;
  for (int i = a; i < b; ++i) {
    offa[i] = run;
    run += deg[i];
    dinv[i] = rsqrtf((float)deg[i]);
  }
  if (t == T - 1) offa[NNODES] = run;
}

__global__ void fill_k(const int* __restrict__ src, const int* __restrict__ dst,
                       const int* __restrict__ offa, int* __restrict__ cur, int* __restrict__ csr) {
  int t = blockIdx.x * 256 + threadIdx.x;
  if (t < NEDGES) {
    int d = dst[t];
    int p = atomicAdd(&cur[d], 1);
    csr[offa[d] + p] = src[t];
  } else if (t < NEDGES + NNODES) {
    int i = t - NEDGES;
    int p = atomicAdd(&cur[i], 1);
    csr[offa[i] + p] = i;   // self loop
  }
}

// ---------------- MFMA GEMM: [M x K] @ WT^T -> [M x NT*16] ----------------
// WT is [NT*16][Kpad] bf16, k-contiguous (pre-transposed, BN-folded).
// A (bf16 path) and B staged via async global_load_lds width=16.
// Epilogue: + extra[col]; optional ReLU; optional *dinv[row] (GCN pre-scale);
// store bf16 to ws, or (SPLIT) fp32 split to backcast/forecast.
template <int NT, bool AF32, bool RELU, bool SPLIT, bool DSCALE>
__global__ __launch_bounds__(256) void gemm_k(const void* __restrict__ Ap, int M, int Kpad,
                                              int lda, int Klim,
                                              const u16* __restrict__ WT,
                                              const float* __restrict__ extra,
                                              const float* __restrict__ dinv,
                                              void* __restrict__ outp, float* __restrict__ out2) {
  __shared__ __align__(16) u16 Alds[64][32];
  __shared__ __align__(16) u16 Blds[NT * 16][32];
  const int tid = threadIdx.x;
  const int wave = tid >> 6, lane = tid & 63;
  const int quad = lane >> 4, l16 = lane & 15;
  const int row0 = blockIdx.x * 64;

  f32x4 acc[NT];
#pragma unroll
  for (int i = 0; i < NT; ++i) acc[i] = (f32x4){0.f, 0.f, 0.f, 0.f};

  const int am = tid >> 2;            // 0..63 tile row
  const int akc = (tid & 3) * 8;      // 0,8,16,24 k-chunk
  const int arow = row0 + am;
  constexpr int BISS = (NT * 16) / 64;  // B staging issues (rows/64)

  for (int k0 = 0; k0 < Kpad; k0 += 32) {
    // --- stage A tile [64][32]: LDS flat offset = tid*16B (row-major) ---
    if constexpr (AF32) {
      uint4 pack = {0u, 0u, 0u, 0u};
      const float* A = (const float*)Ap;
      if (arow < M && (k0 + akc) < Klim) {
        const float* p = A + (size_t)arow * lda + k0 + akc;
        float4 fa = *(const float4*)p;
        float4 fb = *(const float4*)(p + 4);
        pack.x = (uint32_t)f2b(fa.x) | ((uint32_t)f2b(fa.y) << 16);
        pack.y = (uint32_t)f2b(fa.z) | ((uint32_t)f2b(fa.w) << 16);
        pack.z = (uint32_t)f2b(fb.x) | ((uint32_t)f2b(fb.y) << 16);
        pack.w = (uint32_t)f2b(fb.z) | ((uint32_t)f2b(fb.w) << 16);
      }
      *(uint4*)&Alds[am][akc] = pack;
    } else {
      const u16* A = (const u16*)Ap;
      if (arow < M)
        gl2lds16(A + (size_t)arow * lda + k0 + akc, &Alds[0][0] + (size_t)tid * 8);
      // rows >= M: stale LDS feeds only discarded acc rows
    }
    // --- stage B tile [NT*16][32]: issue i covers rows i*64+(tid>>2) ---
#pragma unroll
    for (int i = 0; i < BISS; ++i)
      gl2lds16(WT + (size_t)(i * 64 + am) * Kpad + k0 + akc,
               &Blds[0][0] + (size_t)i * 2048 + (size_t)tid * 8);
    __syncthreads();   // drains vmcnt -> LDS writes visible
    short8 av = *(const short8*)&Alds[wave * 16 + l16][quad * 8];
#pragma unroll
    for (int nt = 0; nt < NT; ++nt) {
      short8 bv = *(const short8*)&Blds[nt * 16 + l16][quad * 8];
      acc[nt] = __builtin_amdgcn_mfma_f32_16x16x32_bf16(av, bv, acc[nt], 0, 0, 0);
    }
    __syncthreads();
  }

  // --- epilogue: C/D layout col = lane&15, row = quad*4 + reg ---
#pragma unroll
  for (int nt = 0; nt < NT; ++nt) {
#pragma unroll
    for (int r = 0; r < 4; ++r) {
      int row = row0 + wave * 16 + quad * 4 + r;
      if (row >= M) continue;
      int col = nt * 16 + l16;
      float v = acc[nt][r] + extra[col];
      if constexpr (RELU) v = fmaxf(v, 0.f);
      if constexpr (DSCALE) v *= dinv[row];   // GCN: pre-scale row by dinv[src]
      if constexpr (SPLIT) {
        if (col < 168) ((float*)outp)[(size_t)row * 168 + col] = v;
        else ((float*)out2)[(size_t)row * 24 + (col - 168)] = v;
      } else {
        ((u16*)outp)[(size_t)row * (NT * 16) + col] = f2b(v);
      }
    }
  }
}

// ---------------- BN stats: per-feature sum / sumsq ----------------
__global__ __launch_bounds__(256) void stats_k(const u16* __restrict__ a, int M,
                                               float* __restrict__ st) {
  int t = threadIdx.x;
  int r0 = blockIdx.x * 64;
  int r1 = min(r0 + 64, M);
  float s = 0.f, q = 0.f;
  for (int r = r0; r < r1; ++r) {
    float v = b2f(a[(size_t)r * HD + t]);
    s += v;
    q += v * v;
  }
  atomicAdd(&st[t], s);
  atomicAdd(&st[HD + t], q);
}

// ---------------- fold BN(stats,gamma,beta) into next weight ----------------
__global__ __launch_bounds__(256) void fold_k(const float* __restrict__ st, float invM,
                                              const float* __restrict__ gamma,
                                              const float* __restrict__ beta,
                                              const float* __restrict__ W, int ncols,
                                              const float* __restrict__ bias,
                                              u16* __restrict__ WT, float* __restrict__ extra) {
  int n = blockIdx.x, k = threadIdx.x;
  float m = st[k] * invM;
  float v = st[HD + k] * invM - m * m;
  float sc = gamma[k] * rsqrtf(v + EPSV);
  float sh = beta[k] - m * sc;
  float w = W[(size_t)k * ncols + n];
  WT[(size_t)n * HD + k] = f2b(sc * w);
  __shared__ float red[256];
  red[k] = sh * w;
  __syncthreads();
  for (int d = 128; d > 0; d >>= 1) {
    if (k < d) red[k] += red[k + d];
    __syncthreads();
  }
  if (k == 0) extra[n] = (bias ? bias[n] : 0.f) + red[0];
}

// ---------------- GCN aggregation: one wave per dst node ----------------
// xw rows are PRE-SCALED by dinv[src] in the gemm epilogue, so the inner
// loop is a pure gather-sum. 8-deep software pipeline to hide gather latency.
__global__ __launch_bounds__(256) void agg_k(const int* __restrict__ csr, const int* __restrict__ offa,
                                             const float* __restrict__ dinv, const u16* __restrict__ xw,
                                             const float* __restrict__ gb, u16* __restrict__ out) {
  int wave = threadIdx.x >> 6, lane = threadIdx.x & 63;
  int dst = blockIdx.x * 4 + wave;
  if (dst >= NNODES) return;
  int p0 = offa[dst], p1 = offa[dst + 1];
  const int c = lane * 4;
  float a0 = 0.f, a1 = 0.f, a2 = 0.f, a3 = 0.f;
  int p = p0;
#define ACCUM(vv)                              \
  a0 += b2f((u16)((vv).x & 0xffffu));          \
  a1 += b2f((u16)((vv).x >> 16));              \
  a2 += b2f((u16)((vv).y & 0xffffu));          \
  a3 += b2f((u16)((vv).y >> 16));
  for (; p + 8 <= p1; p += 8) {
    int s0 = csr[p + 0], s1 = csr[p + 1], s2 = csr[p + 2], s3 = csr[p + 3];
    int s4 = csr[p + 4], s5 = csr[p + 5], s6 = csr[p + 6], s7 = csr[p + 7];
    uint2 v0 = *(const uint2*)&xw[(size_t)s0 * HD + c];
    uint2 v1 = *(const uint2*)&xw[(size_t)s1 * HD + c];
    uint2 v2 = *(const uint2*)&xw[(size_t)s2 * HD + c];
    uint2 v3 = *(const uint2*)&xw[(size_t)s3 * HD + c];
    uint2 v4 = *(const uint2*)&xw[(size_t)s4 * HD + c];
    uint2 v5 = *(const uint2*)&xw[(size_t)s5 * HD + c];
    uint2 v6 = *(const uint2*)&xw[(size_t)s6 * HD + c];
    uint2 v7 = *(const uint2*)&xw[(size_t)s7 * HD + c];
    ACCUM(v0); ACCUM(v1); ACCUM(v2); ACCUM(v3);
    ACCUM(v4); ACCUM(v5); ACCUM(v6); ACCUM(v7);
  }
  for (; p < p1; ++p) {
    int s = csr[p];
    uint2 v = *(const uint2*)&xw[(size_t)s * HD + c];
    ACCUM(v);
  }
#undef ACCUM
  float dd = dinv[dst];
  float4 gv = *(const float4*)&gb[c];
  float r0 = fmaxf(dd * a0 + gv.x, 0.f);
  float r1 = fmaxf(dd * a1 + gv.y, 0.f);
  float r2 = fmaxf(dd * a2 + gv.z, 0.f);
  float r3 = fmaxf(dd * a3 + gv.w, 0.f);
  uint2 o;
  o.x = (uint32_t)f2b(r0) | ((uint32_t)f2b(r1) << 16);
  o.y = (uint32_t)f2b(r2) | ((uint32_t)f2b(r3) << 16);
  *(uint2*)&out[(size_t)dst * HD + c] = o;
}

// ---------------- launch ----------------

extern "C" void kernel_launch(void* const* d_in, const int* in_sizes, int n_in,
                              void* d_out, int out_size, void* d_ws, size_t ws_size,
                              hipStream_t stream) {
  const float* x = (const float*)d_in[0];
  const int* ei = (const int*)d_in[1];
  const float* w1 = (const float*)d_in[2];
  const float* b1 = (const float*)d_in[3];
  const float* g1 = (const float*)d_in[4];
  const float* bt1 = (const float*)d_in[5];
  const float* w2 = (const float*)d_in[6];
  const float* b2 = (const float*)d_in[7];
  const float* g2 = (const float*)d_in[8];
  const float* bt2 = (const float*)d_in[9];
  const float* gw1 = (const float*)d_in[10];
  const float* gb1 = (const float*)d_in[11];
  const float* gg1 = (const float*)d_in[12];
  const float* gbt1 = (const float*)d_in[13];
  const float* gw2 = (const float*)d_in[14];
  const float* gb2 = (const float*)d_in[15];
  const float* gg2 = (const float*)d_in[16];
  const float* gbt2 = (const float*)d_in[17];
  const float* tbW = (const float*)d_in[18];
  const float* tfW = (const float*)d_in[19];
  const float* bb = (const float*)d_in[20];
  const float* bfb = (const float*)d_in[21];
  const int* esrc = ei;
  const int* edst = ei + NEDGES;

  char* wsp = (char*)d_ws;
  size_t off = 0;
  auto alloc = [&](size_t b) {
    void* p = wsp + off;
    off += (b + 511) & ~(size_t)511;
    return p;
  };
  u16* buf1 = (u16*)alloc((size_t)NNODES * HD * 2);
  u16* buf2 = (u16*)alloc((size_t)NNODES * HD * 2);
  int* csr = (int*)alloc((size_t)(NEDGES + NNODES) * 4);
  int* deg = (int*)alloc((size_t)NNODES * 4);
  int* cur = (int*)alloc((size_t)NNODES * 4);
  int* offa = (int*)alloc((size_t)(NNODES + 1) * 4);
  float* dinv = (float*)alloc((size_t)NNODES * 4);
  float* st = (float*)alloc(4 * 512 * 4);
  u16* W1T = (u16*)alloc(256 * 192 * 2);
  u16* WT = (u16*)alloc(256 * 256 * 2);
  float* Mc = (float*)alloc(256 * 192 * 4);
  float* extra = (float*)alloc(256 * 4);

  float* backc = (float*)d_out;
  float* forec = backc + (size_t)NNODES * 168;
  const float invM = 1.0f / (float)NNODES;

  const int GB = (NNODES + 63) / 64;  // 782

  init_k<<<196, 256, 0, stream>>>(deg, cur, st);
  cw1_k<<<256, 192, 0, stream>>>(w1, W1T);
  mc_k<<<256, 192, 0, stream>>>(tbW, tfW, bb, bfb, Mc);
  count_k<<<NEDGES / 256, 256, 0, stream>>>(edst, deg);
  scan_k<<<1, 1024, 0, stream>>>(deg, offa, dinv);
  fill_k<<<(NEDGES + NNODES + 255) / 256, 256, 0, stream>>>(esrc, edst, offa, cur, csr);

  // MLP layer 1: a1 = ReLU(x@w1 + b1)
  gemm_k<16, true, true, false, false><<<GB, 256, 0, stream>>>(x, NNODES, 192, 168, 168, W1T, b1, nullptr, buf1, nullptr);
  stats_k<<<GB, 256, 0, stream>>>(buf1, NNODES, st);
  // fold BN1 into w2 (+b2)
  fold_k<<<256, 256, 0, stream>>>(st, invM, g1, bt1, w2, 256, b2, WT, extra);
  // MLP layer 2: a2 = ReLU(BN1(a1)@w2 + b2)
  gemm_k<16, false, true, false, false><<<GB, 256, 0, stream>>>(buf1, NNODES, 256, 256, 256, WT, extra, nullptr, buf2, nullptr);
  stats_k<<<GB, 256, 0, stream>>>(buf2, NNODES, st + 512);
  // fold BN2 into gw1 (no bias: gb1 added after aggregation)
  fold_k<<<256, 256, 0, stream>>>(st + 512, invM, g2, bt2, gw1, 256, nullptr, WT, extra);
  // xw1 = (BN2(a2)@gw1) * dinv[row]  (pre-scaled for aggregation)
  gemm_k<16, false, false, false, true><<<GB, 256, 0, stream>>>(buf2, NNODES, 256, 256, 256, WT, extra, dinv, buf1, nullptr);
  // g1a = ReLU(dinv[dst] * sum(xw1[src]) + gb1)
  agg_k<<<12500, 256, 0, stream>>>(csr, offa, dinv, buf1, gb1, buf2);
  stats_k<<<GB, 256, 0, stream>>>(buf2, NNODES, st + 1024);
  // fold BN3 into gw2
  fold_k<<<256, 256, 0, stream>>>(st + 1024, invM, gg1, gbt1, gw2, 256, nullptr, WT, extra);
  // xw2 = (BN3(g1a)@gw2) * dinv[row]
  gemm_k<16, false, false, false, true><<<GB, 256, 0, stream>>>(buf2, NNODES, 256, 256, 256, WT, extra, dinv, buf1, nullptr);
  // g2a = ReLU(dinv[dst] * sum(xw2[src]) + gb2)
  agg_k<<<12500, 256, 0, stream>>>(csr, offa, dinv, buf1, gb2, buf2);
  stats_k<<<GB, 256, 0, stream>>>(buf2, NNODES, st + 1536);
  // fold BN4 into Mc [256][192]
  fold_k<<<192, 256, 0, stream>>>(st + 1536, invM, gg2, gbt2, Mc, 192, nullptr, WT, extra);
  // final: [backcast || forecast] = BN4(g2a) @ Mc
  gemm_k<12, false, false, true, false><<<GB, 256, 0, stream>>>(buf2, NNODES, 256, 256, 256, WT, extra, nullptr, backc, forec);
}